// Round 5
// baseline (175.746 us; speedup 1.0000x reference)
//
#include <hip/hip_runtime.h>
#include <math.h>

// RiemannianMetric: g[b,s,i,j] = sum_r tanh(x·W[r]+b[r])^2 A[r,i]A[r,j] + lam*I
// B=2 S=1024 DIM=256 RANK=32. Output 512 MiB f32 -> store floor ~80us @6.7TB/s.
// R5: MFMA. G = V^T V with V[k][j] = tanh_k * A[k][j] in bf16 (error ~1e-4 << 2.2e-3).
// Per wave: 20 ds_read_b128 + 64 mfma_16x16x32_bf16 + 256 nt stores. Compute+LDS ~10us
// total -> pure store-drain. LDS slab layout vt[k>>3][j][k&7]: b128 reads/writes
// conflict-free (8-lane groups span all 32 banks). Symmetric G => robust to any
// row/col convention swap in MFMA frag layouts.

constexpr int DIM  = 256;
constexpr int RANK = 32;

typedef float f32x4 __attribute__((ext_vector_type(4)));
typedef short s16x8 __attribute__((ext_vector_type(8))); // 8 bf16 = 4 VGPR

static __device__ __forceinline__ unsigned short f2bf(float f) {
    unsigned int u = __builtin_bit_cast(unsigned int, f);
    u = (u + 0x7FFFu + ((u >> 16) & 1u)) >> 16; // RNE
    return (unsigned short)u;
}

__global__ __launch_bounds__(256, 2) void riemannian_metric_kernel(
    const float* __restrict__ x,          // [B*S, DIM]
    const float* __restrict__ A,          // [RANK, DIM]
    const float* __restrict__ log_lambda, // [1]
    const float* __restrict__ W,          // [RANK, DIM]
    const float* __restrict__ bvec,       // [RANK]
    float* __restrict__ out)              // [B*S, DIM, DIM]
{
    __shared__ float xs[DIM];
    __shared__ float sw[RANK];
    __shared__ alignas(16) unsigned short vt[4][DIM][8]; // [k>>3][j][k&7], bf16, 16KB

    const int tid  = threadIdx.x;
    const int pos  = blockIdx.x;
    const int lane = tid & 63;
    const int rs   = tid >> 6;   // wave id: rows 64rs..64rs+63

    xs[tid] = x[(size_t)pos * DIM + tid];
    __syncthreads();

    // sw[r] = tanh(x·W[r]+b[r]) — signed; folded into BOTH factors -> squares
    {
        const int r = tid >> 3, seg = tid & 7;
        const f32x4* wr4 = (const f32x4*)(W + r * DIM + seg * 32);
        const f32x4* xr4 = (const f32x4*)(xs + seg * 32);
        float dot = 0.f;
        #pragma unroll
        for (int q = 0; q < 8; ++q) {
            f32x4 wv = wr4[q], xv = xr4[q];
            dot = fmaf(wv.x, xv.x, dot);
            dot = fmaf(wv.y, xv.y, dot);
            dot = fmaf(wv.z, xv.z, dot);
            dot = fmaf(wv.w, xv.w, dot);
        }
        dot += __shfl_xor(dot, 1);
        dot += __shfl_xor(dot, 2);
        dot += __shfl_xor(dot, 4);
        if (seg == 0) sw[r] = tanhf(dot + bvec[r]);
    }
    __syncthreads();

    // build V^T slabs: vt[kg][j][e] = bf16(sw[8kg+e] * A[8kg+e][j]), j = tid
    // A reads coalesced per k (1KB row across threads); ds_write_b128 conflict-free.
    #pragma unroll
    for (int kg = 0; kg < 4; ++kg) {
        s16x8 pk;
        #pragma unroll
        for (int e = 0; e < 8; ++e) {
            const int k = kg * 8 + e;
            pk[e] = (short)f2bf(sw[k] * A[k * DIM + tid]);
        }
        *(s16x8*)&vt[kg][tid][0] = pk;
    }
    __syncthreads();

    // fragment loads: lane holds k = (lane>>4)*8+e of column (tile*16 + (lane&15))
    const int kg = lane >> 4, cl = lane & 15;
    s16x8 bfr[16]; // all 16 col-tile frags (covers every tile; static-indexed)
    #pragma unroll
    for (int u = 0; u < 16; ++u)
        bfr[u] = *(const s16x8*)&vt[kg][u * 16 + cl][0];
    s16x8 afr[4];  // this wave's 4 row-tile frags (same layout, G symmetric)
    #pragma unroll
    for (int t = 0; t < 4; ++t)
        afr[t] = *(const s16x8*)&vt[kg][rs * 64 + t * 16 + cl][0];

    const float lam = expf(log_lambda[0]);
    // C/D frag: col = lane&15, row = (lane>>4)*4 + e  (transpose-safe: G symmetric)
    float* base = out + (size_t)pos * DIM * DIM
                      + (size_t)(rs * 64 + kg * 4) * DIM + cl;

    #pragma unroll
    for (int t = 0; t < 4; ++t) {
        #pragma unroll
        for (int u = 0; u < 16; ++u) {
            f32x4 acc = (f32x4)(0.f);
            acc = __builtin_amdgcn_mfma_f32_16x16x32_bf16(afr[t], bfr[u], acc, 0, 0, 0);
            float* p = base + (size_t)(t * 16) * DIM + u * 16;
            if (u == rs * 4 + t) { // wave-uniform: only diagonal tiles pay the check
                #pragma unroll
                for (int e = 0; e < 4; ++e) {
                    float v = acc[e];
                    if (kg * 4 + e == cl) v += lam;
                    __builtin_nontemporal_store(v, p + (size_t)e * DIM);
                }
            } else {
                #pragma unroll
                for (int e = 0; e < 4; ++e)
                    __builtin_nontemporal_store(acc[e], p + (size_t)e * DIM);
            }
        }
    }
}

extern "C" void kernel_launch(void* const* d_in, const int* in_sizes, int n_in,
                              void* d_out, int out_size, void* d_ws, size_t ws_size,
                              hipStream_t stream) {
    const float* x          = (const float*)d_in[0];
    const float* A          = (const float*)d_in[1];
    const float* log_lambda = (const float*)d_in[2];
    const float* W          = (const float*)d_in[3];
    const float* bvec       = (const float*)d_in[4];
    float* out              = (float*)d_out;

    const int n_pos = in_sizes[0] / DIM; // B*S = 2048
    riemannian_metric_kernel<<<n_pos, 256, 0, stream>>>(x, A, log_lambda, W, bvec, out);
}

// Round 6
// 170.429 us; speedup vs baseline: 1.0312x; 1.0312x over previous
//
#include <hip/hip_runtime.h>
#include <math.h>

// RiemannianMetric: g[b,s,i,j] = sum_r tanh(x·W[r]+b[r])^2 A[r,i]A[r,j] + lam*I
// B=2 S=1024 DIM=256 RANK=32. Output 512 MiB f32 -> store floor ~80us @6.7TB/s.
// R6: MFMA with SWAPPED operands. mfma(frag_u, frag_t) yields the transposed tile,
// so lane (q,cl) reg e holds G[t*16+cl][u*16+4q+e] = 4 CONSECUTIVE cols of one row
// -> dwordx4 nt stores, 1KB/wave-instr (fixes R5's 256 scalar stores / 256B-instr).
// Per wave: 20 ds_read_b128 + 64 mfma_16x16x32_bf16 + 64 dwordx4 nt stores.

constexpr int DIM  = 256;
constexpr int RANK = 32;

typedef float f32x4 __attribute__((ext_vector_type(4)));
typedef short s16x8 __attribute__((ext_vector_type(8))); // 8 bf16 = 4 VGPR

static __device__ __forceinline__ unsigned short f2bf(float f) {
    unsigned int u = __builtin_bit_cast(unsigned int, f);
    u = (u + 0x7FFFu + ((u >> 16) & 1u)) >> 16; // RNE
    return (unsigned short)u;
}

__global__ __launch_bounds__(256, 2) void riemannian_metric_kernel(
    const float* __restrict__ x,          // [B*S, DIM]
    const float* __restrict__ A,          // [RANK, DIM]
    const float* __restrict__ log_lambda, // [1]
    const float* __restrict__ W,          // [RANK, DIM]
    const float* __restrict__ bvec,       // [RANK]
    float* __restrict__ out)              // [B*S, DIM, DIM]
{
    __shared__ float xs[DIM];
    __shared__ float sw[RANK];
    __shared__ alignas(16) unsigned short vt[4][DIM][8]; // [k>>3][j][k&7], bf16, 16KB

    const int tid  = threadIdx.x;
    const int pos  = blockIdx.x;
    const int lane = tid & 63;
    const int rs   = tid >> 6;   // wave id: rows 64rs..64rs+63

    xs[tid] = x[(size_t)pos * DIM + tid];
    __syncthreads();

    // sw[r] = tanh(x·W[r]+b[r]) — signed; folded into BOTH factors -> squares
    {
        const int r = tid >> 3, seg = tid & 7;
        const f32x4* wr4 = (const f32x4*)(W + r * DIM + seg * 32);
        const f32x4* xr4 = (const f32x4*)(xs + seg * 32);
        float dot = 0.f;
        #pragma unroll
        for (int q = 0; q < 8; ++q) {
            f32x4 wv = wr4[q], xv = xr4[q];
            dot = fmaf(wv.x, xv.x, dot);
            dot = fmaf(wv.y, xv.y, dot);
            dot = fmaf(wv.z, xv.z, dot);
            dot = fmaf(wv.w, xv.w, dot);
        }
        dot += __shfl_xor(dot, 1);
        dot += __shfl_xor(dot, 2);
        dot += __shfl_xor(dot, 4);
        if (seg == 0) sw[r] = tanhf(dot + bvec[r]);
    }
    __syncthreads();

    // build V^T slabs: vt[kg][j][e] = bf16(sw[8kg+e] * A[8kg+e][j]), j = tid
    #pragma unroll
    for (int kg = 0; kg < 4; ++kg) {
        s16x8 pk;
        #pragma unroll
        for (int e = 0; e < 8; ++e) {
            const int k = kg * 8 + e;
            pk[e] = (short)f2bf(sw[k] * A[k * DIM + tid]);
        }
        *(s16x8*)&vt[kg][tid][0] = pk;
    }
    __syncthreads();

    // fragment loads: lane (kg=lane>>4, cl=lane&15) holds k = kg*8+e of col tile*16+cl
    const int kg = lane >> 4, cl = lane & 15;
    const int q  = kg;           // C-frag row group alias
    s16x8 bfr[16]; // all 16 col-tile frags (static-indexed)
    #pragma unroll
    for (int u = 0; u < 16; ++u)
        bfr[u] = *(const s16x8*)&vt[kg][u * 16 + cl][0];
    s16x8 afr[4];  // this wave's 4 row-tile frags (separate array: static indices)
    #pragma unroll
    for (int t = 0; t < 4; ++t)
        afr[t] = *(const s16x8*)&vt[kg][rs * 64 + t * 16 + cl][0];

    const float lam = expf(log_lambda[0]);
    const bool on_diag_lane = (q == (cl >> 2));
    const int  diag_slot    = cl & 3;

    // swapped-operand MFMA: D = mfma(bfr[u], afr[t]) -> lane (q,cl) reg e =
    // G[rs*64 + t*16 + cl][u*16 + 4q + e]  (4 consecutive cols of one row)
    float* base = out + (size_t)pos * DIM * DIM + (size_t)(rs * 64 + cl) * DIM + q * 4;

    #pragma unroll
    for (int t = 0; t < 4; ++t) {
        float* rowp = base + (size_t)(t * 16) * DIM;
        #pragma unroll
        for (int u = 0; u < 16; ++u) {
            f32x4 acc = (f32x4)(0.f);
            acc = __builtin_amdgcn_mfma_f32_16x16x32_bf16(bfr[u], afr[t], acc, 0, 0, 0);
            if (u == rs * 4 + t && on_diag_lane) // diagonal tile, wave-uniform check
                acc[diag_slot] += lam;
            __builtin_nontemporal_store(acc, (f32x4*)(rowp + u * 16)); // 1KB/wave
        }
    }
}

extern "C" void kernel_launch(void* const* d_in, const int* in_sizes, int n_in,
                              void* d_out, int out_size, void* d_ws, size_t ws_size,
                              hipStream_t stream) {
    const float* x          = (const float*)d_in[0];
    const float* A          = (const float*)d_in[1];
    const float* log_lambda = (const float*)d_in[2];
    const float* W          = (const float*)d_in[3];
    const float* bvec       = (const float*)d_in[4];
    float* out              = (float*)d_out;

    const int n_pos = in_sizes[0] / DIM; // B*S = 2048
    riemannian_metric_kernel<<<n_pos, 256, 0, stream>>>(x, A, log_lambda, W, bvec, out);
}

// Round 7
// 162.711 us; speedup vs baseline: 1.0801x; 1.0474x over previous
//
#include <hip/hip_runtime.h>
#include <math.h>

// RiemannianMetric: g[b,s,i,j] = sum_r tanh(x·W[r]+b[r])^2 A[r,i]A[r,j] + lam*I
// B=2 S=1024 DIM=256 RANK=32. Output 537 MB f32 -> store floor ~80us @6.7TB/s.
// R7: R6's MFMA (validated) + per-wave LDS transpose epilogue so global stores are
// CONTIGUOUS 512-B segments (R5/R6's 64-B C-frag segments caused line RMW ~ half BW).
// Per wave/position: 64 mfma + 128 LDS b128 (swizzled, conflict-free) + 64 nt dwordx4.

constexpr int DIM  = 256;
constexpr int RANK = 32;

typedef float f32x4 __attribute__((ext_vector_type(4)));
typedef short s16x8 __attribute__((ext_vector_type(8))); // 8 bf16 = 4 VGPR

static __device__ __forceinline__ unsigned short f2bf(float f) {
    unsigned int u = __builtin_bit_cast(unsigned int, f);
    u = (u + 0x7FFFu + ((u >> 16) & 1u)) >> 16; // RNE
    return (unsigned short)u;
}

__global__ __launch_bounds__(256, 2) void riemannian_metric_kernel(
    const float* __restrict__ x,          // [B*S, DIM]
    const float* __restrict__ A,          // [RANK, DIM]
    const float* __restrict__ log_lambda, // [1]
    const float* __restrict__ W,          // [RANK, DIM]
    const float* __restrict__ bvec,       // [RANK]
    float* __restrict__ out)              // [B*S, DIM, DIM]
{
    __shared__ float xs[DIM];
    __shared__ float sw[RANK];
    __shared__ alignas(16) unsigned short vt[4][DIM][8]; // [k>>3][j][k&7] bf16, 16KB
    __shared__ alignas(16) float stage[4][16 * 128];     // per-wave 8KB transpose buf

    const int tid  = threadIdx.x;
    const int pos  = blockIdx.x;
    const int lane = tid & 63;
    const int rs   = tid >> 6;   // wave id: rows 64rs..64rs+63

    xs[tid] = x[(size_t)pos * DIM + tid];
    __syncthreads();

    // sw[r] = tanh(x·W[r]+b[r]) — signed; folded into BOTH factors -> squares
    {
        const int r = tid >> 3, seg = tid & 7;
        const f32x4* wr4 = (const f32x4*)(W + r * DIM + seg * 32);
        const f32x4* xr4 = (const f32x4*)(xs + seg * 32);
        float dot = 0.f;
        #pragma unroll
        for (int qq = 0; qq < 8; ++qq) {
            f32x4 wv = wr4[qq], xv = xr4[qq];
            dot = fmaf(wv.x, xv.x, dot);
            dot = fmaf(wv.y, xv.y, dot);
            dot = fmaf(wv.z, xv.z, dot);
            dot = fmaf(wv.w, xv.w, dot);
        }
        dot += __shfl_xor(dot, 1);
        dot += __shfl_xor(dot, 2);
        dot += __shfl_xor(dot, 4);
        if (seg == 0) sw[r] = tanhf(dot + bvec[r]);
    }
    __syncthreads();

    // build V^T slabs: vt[kg][j][e] = bf16(sw[8kg+e] * A[8kg+e][j]), j = tid
    #pragma unroll
    for (int g = 0; g < 4; ++g) {
        s16x8 pk;
        #pragma unroll
        for (int e = 0; e < 8; ++e) {
            const int k = g * 8 + e;
            pk[e] = (short)f2bf(sw[k] * A[k * DIM + tid]);
        }
        *(s16x8*)&vt[g][tid][0] = pk;
    }
    __syncthreads();

    // fragment loads: lane (kg=lane>>4, cl=lane&15) holds k = kg*8+e of col tile*16+cl
    const int kg = lane >> 4, cl = lane & 15;
    const int q  = kg;           // C-frag row-group alias
    s16x8 bfr[16];
    #pragma unroll
    for (int u = 0; u < 16; ++u)
        bfr[u] = *(const s16x8*)&vt[kg][u * 16 + cl][0];
    s16x8 afr[4];
    #pragma unroll
    for (int t = 0; t < 4; ++t)
        afr[t] = *(const s16x8*)&vt[kg][rs * 64 + t * 16 + cl][0];

    const float lam = expf(log_lambda[0]);
    const bool on_diag_lane = (q == (cl >> 2));
    const int  diag_slot    = cl & 3;

    float* sbuf = stage[rs];
    // stage addressing: idx = row*128 + col, swizzle ^((row&7)<<2) (float units)
    const int wbase = cl * 128 + 4 * q;      // write: row=cl, col=uu*16+4q
    const int wswz  = (cl & 7) << 2;
    const int rrow0 = lane >> 5;             // read: 2 rows per instruction
    const int rcol  = (lane & 31) * 4;

    float* gbase = out + (size_t)pos * DIM * DIM;

    #pragma unroll 1
    for (int t = 0; t < 4; ++t) {
        #pragma unroll 1
        for (int half = 0; half < 2; ++half) {
            // 8 MFMAs -> 16x128 sub-tile into swizzled stage (ds_write_b128, no conflicts)
            #pragma unroll
            for (int uu = 0; uu < 8; ++uu) {
                const int u = half * 8 + uu;
                f32x4 acc = (f32x4)(0.f);
                acc = __builtin_amdgcn_mfma_f32_16x16x32_bf16(bfr[u], afr[t], acc, 0, 0, 0);
                if (u == rs * 4 + t && on_diag_lane) // diagonal tile of G
                    acc[diag_slot] += lam;
                *(f32x4*)&sbuf[(wbase + uu * 16) ^ wswz] = acc;
            }
            // read back 2 full rows per instruction -> contiguous 512B-segment stores
            #pragma unroll
            for (int m = 0; m < 8; ++m) {
                const int row = 2 * m + rrow0;
                f32x4 v = *(const f32x4*)&sbuf[(row * 128 + rcol) ^ ((row & 7) << 2)];
                float* gp = gbase + (size_t)(rs * 64 + t * 16 + row) * DIM
                                  + half * 128 + rcol;
                __builtin_nontemporal_store(v, (f32x4*)gp);
            }
        }
    }
}

extern "C" void kernel_launch(void* const* d_in, const int* in_sizes, int n_in,
                              void* d_out, int out_size, void* d_ws, size_t ws_size,
                              hipStream_t stream) {
    const float* x          = (const float*)d_in[0];
    const float* A          = (const float*)d_in[1];
    const float* log_lambda = (const float*)d_in[2];
    const float* W          = (const float*)d_in[3];
    const float* bvec       = (const float*)d_in[4];
    float* out              = (float*)d_out;

    const int n_pos = in_sizes[0] / DIM; // B*S = 2048
    riemannian_metric_kernel<<<n_pos, 256, 0, stream>>>(x, A, log_lambda, W, bvec, out);
}